// Round 2
// baseline (725.295 us; speedup 1.0000x reference)
//
#include <hip/hip_runtime.h>
#include <hip/hip_bf16.h>

typedef unsigned short ushort_t;
typedef __attribute__((ext_vector_type(8))) short short8v;
typedef __attribute__((ext_vector_type(4))) float float4v;

#define NP   4
#define NB   128
#define NIMG 512   // NP*NB
#define CIN  32
#define KOUT 64

// fp32 -> bf16 round-to-nearest-even
__device__ __forceinline__ ushort_t f2bf(float f) {
    unsigned u = __float_as_uint(f);
    unsigned r = u + 0x7fffu + ((u >> 16) & 1u);
    return (ushort_t)(r >> 16);
}

// ---------------------------------------------------------------------------
// Kernel 1: w_t[rs][outk][c] (bf16) from fp32 conv_w[outk][c][r][s], rs=r*3+s.
// B^T (n-major, k-inner) layout for the MFMA B-fragment.
// ---------------------------------------------------------------------------
__global__ void prep_kernel(const float* __restrict__ conv_w,
                            ushort_t* __restrict__ w_t) {
    int i = blockIdx.x * 256 + threadIdx.x;
    if (i < 9 * KOUT * CIN) {
        int rs  = i >> 11;
        int rem = i & 2047;
        int ko  = rem >> 5;
        int c   = rem & 31;
        w_t[i] = f2bf(conv_w[ko * 288 + c * 9 + rs]);
    }
}

// ---------------------------------------------------------------------------
// Kernel 2 v3: fused circular 3x3 conv (bf16 MFMA) + bias + ReLU + pool
// partials. 16 output rows per block (18 staged: halo 1.125x vs 1.25x for
// 8-row strips) -> x HBM traffic 335.5 -> 301.1 MB. The K-loop runs as two
// 8-row passes reusing the same acc registers; pool sums accumulate across
// passes so VGPR count is unchanged vs the 8-row version.
// LDS: xs[(row*66+col)*32 + (c ^ (((col>>3)&3)<<3))] — XOR swizzle keeps
// 8-channel A-fragments contiguous (single ds_read_b128) while spreading
// staging writes across banks. 76 KB LDS -> 2 blocks/CU (unchanged: acc
// AGPRs already cap us at 2 waves/SIMD).
// ---------------------------------------------------------------------------
__global__ __launch_bounds__(256, 2)
void conv_pool_kernel(const float* __restrict__ x,
                      const float* __restrict__ conv_b,
                      const ushort_t* __restrict__ w_t,
                      float* __restrict__ partials) {
    __shared__ ushort_t xs[18 * 66 * 32];   // 76,032 B
    __shared__ float psum[4][64];

    const int tid = threadIdx.x;
    const int n   = blockIdx.x >> 2;        // image 0..511
    const int h0  = (blockIdx.x & 3) << 4;  // first output row (0,16,32,48)
    const long xbase = (long)n * (CIN * 64 * 64);

    // ---- stage rows h0-1..h0+16 (circular): fp32 NCHW -> swizzled bf16
    // thread owns fixed (wq: 4-col chunk 0..15, cg: 4-ch group 0..7) and rows
    // lr0, lr0+2, ..., lr0+16 (lr0 = tid>>7): 9 rows, in 3 batches of 3 so
    // 12 float4 loads are in flight per batch.
    {
        const int wq  = tid & 15;
        const int cg  = (tid >> 4) & 7;
        const int lr0 = tid >> 7;           // 0 or 1

        union F4 { float4 v; float f[4]; };
        #pragma unroll
        for (int kb = 0; kb < 3; ++kb) {
            F4 L[3][4];
            #pragma unroll
            for (int k = 0; k < 3; ++k) {
                const int lr = lr0 + 2 * (kb * 3 + k);
                const int gh = (h0 + lr + 63) & 63;
                #pragma unroll
                for (int cc = 0; cc < 4; ++cc)
                    L[k][cc].v = *(const float4*)(x + xbase +
                                ((cg * 4 + cc) * 4096 + gh * 64 + wq * 4));
            }
            #pragma unroll
            for (int k = 0; k < 3; ++k) {
                const int lr = lr0 + 2 * (kb * 3 + k);
                #pragma unroll
                for (int j = 0; j < 4; ++j) {
                    int col  = wq * 4 + 1 + j;                 // LDS col = w + 1
                    int cpos = (cg * 4) ^ (((col >> 3) & 3) << 3);
                    union { uint2 v; ushort_t s[4]; } t;
                    t.s[0] = f2bf(L[k][0].f[j]); t.s[1] = f2bf(L[k][1].f[j]);
                    t.s[2] = f2bf(L[k][2].f[j]); t.s[3] = f2bf(L[k][3].f[j]);
                    *(uint2*)&xs[(lr * 66 + col) * 32 + cpos] = t.v;
                    if (wq == 0 && j == 0)   // global w=0 -> halo col 65 (swz=0)
                        *(uint2*)&xs[(lr * 66 + 65) * 32 + cg * 4] = t.v;
                    if (wq == 15 && j == 3)  // global w=63 -> halo col 0 (swz=0)
                        *(uint2*)&xs[(lr * 66 + 0) * 32 + cg * 4] = t.v;
                }
            }
        }
    }
    __syncthreads();

    // ---- MFMA K-loop: 2 passes x 9 taps x K=32 channels ----
    const int lane = tid & 63;
    const int wv   = tid >> 6;
    const int m16  = lane & 15;
    const int q    = lane >> 4;

    int aaddr[8][3];
    #pragma unroll
    for (int mt = 0; mt < 8; ++mt) {
        int lpr = wv * 2 + (mt >> 2);        // pass-local output row 0..7
        int lc  = (mt & 3) * 16 + m16;       // output col 0..63
        #pragma unroll
        for (int s = 0; s < 3; ++s) {
            int col = lc + s;
            int cr  = (q ^ ((col >> 3) & 3)) << 3;
            aaddr[mt][s] = (lpr * 66 + col) * 32 + cr;
        }
    }

    const ushort_t* wt_lane = w_t + (m16 * 32 + (q << 3));

    float bias[4];
    #pragma unroll
    for (int nt = 0; nt < 4; ++nt) bias[nt] = conv_b[nt * 16 + m16];

    float sums[4] = {0.f, 0.f, 0.f, 0.f};

    #pragma unroll
    for (int pass = 0; pass < 2; ++pass) {
        const int rowoff = pass * 8 * (66 * 32);

        float4v accv[8][4];
        #pragma unroll
        for (int mt = 0; mt < 8; ++mt)
            #pragma unroll
            for (int nt = 0; nt < 4; ++nt)
                accv[mt][nt] = (float4v){0.f, 0.f, 0.f, 0.f};

        #pragma unroll
        for (int r = 0; r < 3; ++r) {
            #pragma unroll
            for (int s = 0; s < 3; ++s) {
                const int rs = r * 3 + s;
                short8v bfr[4];
                #pragma unroll
                for (int nt = 0; nt < 4; ++nt)
                    bfr[nt] = *(const short8v*)(wt_lane + (rs * 64 + nt * 16) * 32);
                #pragma unroll
                for (int mt = 0; mt < 8; ++mt) {
                    short8v afr = *(const short8v*)
                        &xs[aaddr[mt][s] + rowoff + r * (66 * 32)];
                    #pragma unroll
                    for (int nt = 0; nt < 4; ++nt)
                        accv[mt][nt] = __builtin_amdgcn_mfma_f32_16x16x32_bf16(
                            afr, bfr[nt], accv[mt][nt], 0, 0, 0);
                }
            }
        }

        // fold this pass into the pool sums (bias + ReLU per pixel)
        #pragma unroll
        for (int nt = 0; nt < 4; ++nt)
            #pragma unroll
            for (int mt = 0; mt < 8; ++mt)
                #pragma unroll
                for (int rg = 0; rg < 4; ++rg)
                    sums[nt] += fmaxf(accv[mt][nt][rg] + bias[nt], 0.f);
    }

    // ---- epilogue: reduce pool partials across lanes/waves ----
    #pragma unroll
    for (int nt = 0; nt < 4; ++nt) {
        float sv = sums[nt];
        sv += __shfl_xor(sv, 16);
        sv += __shfl_xor(sv, 32);
        if (lane < 16) psum[wv][nt * 16 + lane] = sv;
    }
    __syncthreads();
    if (tid < 64)
        partials[(long)blockIdx.x * 64 + tid] =
            psum[0][tid] + psum[1][tid] + psum[2][tid] + psum[3][tid];
}

// ---------------------------------------------------------------------------
// Kernel 3 v2: graph MLP, one block per (batch b, recv node j) -> 512 blocks
// (2 blocks/CU). Each phase is exactly 1 element/thread.
// nodes[p][h] = sum_hb partials[((p*128+b)*4+hb)*64+h] / 4096.
// ---------------------------------------------------------------------------
__global__ __launch_bounds__(256)
void mlp_kernel(const float* __restrict__ partials,
                const float* __restrict__ e_w1, const float* __restrict__ e_b1,
                const float* __restrict__ e_w2, const float* __restrict__ e_b2,
                const float* __restrict__ o_w1, const float* __restrict__ o_b1,
                const float* __restrict__ o_w2, const float* __restrict__ o_b2,
                float* __restrict__ out) {
    __shared__ float nodes_s[256], h1s[256], e2s[256], msgs[64];

    const int tid = threadIdx.x;
    const int b   = blockIdx.x >> 2;   // batch 0..127
    const int j   = blockIdx.x & 3;    // recv node 0..3
    const int i   = tid >> 6;          // send node 0..3 (one per wave)
    const int h   = tid & 63;          // hidden lane

    // nodes for all 4 senders (recv j is one of them)
    {
        const float* pp = partials + (long)((i * 128 + b) * 4) * 64 + h;
        float s = 0.f;
        #pragma unroll
        for (int hb = 0; hb < 4; ++hb) s += pp[hb * 64];
        nodes_s[tid] = s * (1.f / 4096.f);
    }
    __syncthreads();

    // h1 for the 4 edges (i, j): [node_i(send) | node_j(recv)] @ e_w1
    {
        float sum = e_b1[h];
        const float* ni = &nodes_s[i * 64];
        const float* nj = &nodes_s[j * 64];
        #pragma unroll
        for (int k = 0; k < 64; ++k)
            sum += ni[k] * e_w1[k * 64 + h] + nj[k] * e_w1[(64 + k) * 64 + h];
        h1s[tid] = fmaxf(sum, 0.f);
    }
    __syncthreads();

    // e2 = relu(h1 @ e_w2 + e_b2)
    {
        float sum = e_b2[h];
        const float* he = &h1s[i * 64];
        #pragma unroll
        for (int k = 0; k < 64; ++k)
            sum += he[k] * e_w2[k * 64 + h];
        e2s[tid] = fmaxf(sum, 0.f);
    }
    __syncthreads();

    // msg[j] = mean over send axis i
    if (tid < 64)
        msgs[tid] = 0.25f * (e2s[tid] + e2s[64 + tid] +
                             e2s[128 + tid] + e2s[192 + tid]);
    __syncthreads();

    // o1 = relu(msg @ o_w1 + o_b1); out[b][j] = o1 . o_w2 + o_b2 (wave 0)
    if (tid < 64) {
        float sum = o_b1[tid];
        #pragma unroll
        for (int k = 0; k < 64; ++k)
            sum += msgs[k] * o_w1[k * 64 + tid];
        float v = fmaxf(sum, 0.f) * o_w2[tid];
        v += __shfl_xor(v, 1);
        v += __shfl_xor(v, 2);
        v += __shfl_xor(v, 4);
        v += __shfl_xor(v, 8);
        v += __shfl_xor(v, 16);
        v += __shfl_xor(v, 32);
        if (tid == 0) out[b * 4 + j] = v + o_b2[0];
    }
}

// ---------------------------------------------------------------------------
extern "C" void kernel_launch(void* const* d_in, const int* in_sizes, int n_in,
                              void* d_out, int out_size, void* d_ws, size_t ws_size,
                              hipStream_t stream) {
    const float* x      = (const float*)d_in[0];
    const float* conv_w = (const float*)d_in[1];
    const float* conv_b = (const float*)d_in[2];
    const float* e_w1   = (const float*)d_in[3];
    const float* e_b1   = (const float*)d_in[4];
    const float* e_w2   = (const float*)d_in[5];
    const float* e_b2   = (const float*)d_in[6];
    const float* o_w1   = (const float*)d_in[7];
    const float* o_b1   = (const float*)d_in[8];
    const float* o_w2   = (const float*)d_in[9];
    const float* o_b2   = (const float*)d_in[10];

    // ws: [0, 512KB) fp32 pool partials [2048 blocks][64ch]; then w_t bf16
    float*    partials = (float*)d_ws;
    ushort_t* w_t = (ushort_t*)((char*)d_ws + (size_t)NIMG * 4 * 64 * sizeof(float));

    prep_kernel<<<72, 256, 0, stream>>>(conv_w, w_t);
    conv_pool_kernel<<<NIMG * 4, 256, 0, stream>>>(x, conv_b, w_t, partials);
    mlp_kernel<<<NB * NP, 256, 0, stream>>>(partials, e_w1, e_b1, e_w2, e_b2,
                                            o_w1, o_b1, o_w2, o_b2,
                                            (float*)d_out);
}

// Round 3
// 420.919 us; speedup vs baseline: 1.7231x; 1.7231x over previous
//
#include <hip/hip_runtime.h>
#include <hip/hip_bf16.h>

typedef unsigned short ushort_t;
typedef __attribute__((ext_vector_type(8))) short short8v;
typedef __attribute__((ext_vector_type(4))) float float4v;

#define NP   4
#define NB   128
#define NIMG 512   // NP*NB
#define CIN  32
#define KOUT 64

// fp32 -> bf16 round-to-nearest-even
__device__ __forceinline__ ushort_t f2bf(float f) {
    unsigned u = __float_as_uint(f);
    unsigned r = u + 0x7fffu + ((u >> 16) & 1u);
    return (ushort_t)(r >> 16);
}

// ---------------------------------------------------------------------------
// Kernel 1: w_t[rs][outk][c] (bf16) from fp32 conv_w[outk][c][r][s], rs=r*3+s.
// B^T (n-major, k-inner) layout for the MFMA B-fragment.
// ---------------------------------------------------------------------------
__global__ void prep_kernel(const float* __restrict__ conv_w,
                            ushort_t* __restrict__ w_t) {
    int i = blockIdx.x * 256 + threadIdx.x;
    if (i < 9 * KOUT * CIN) {
        int rs  = i >> 11;
        int rem = i & 2047;
        int ko  = rem >> 5;
        int c   = rem & 31;
        w_t[i] = f2bf(conv_w[ko * 288 + c * 9 + rs]);
    }
}

// ---------------------------------------------------------------------------
// Kernel 2 (R1 structure — REVERTED from the 16-row R2 variant).
// R2 post-mortem: 16-row strips + 2-pass shared accumulator exceeded the
// 256-reg unified VGPR+AGPR budget at __launch_bounds__(256,2); the acc tile
// spilled to scratch (rocprof: WRITE_SIZE 1.07 GB vs 512 KB ideal, FETCH
// +370 MB of scratch re-reads, all pipes <10%, 448 us/dispatch). This 8-row
// structure fits exactly: 128 AGPR acc + 128 VGPR. DO NOT grow the
// accumulator live range or add state across the MFMA loop.
//
// Fused circular 3x3 conv (bf16 MFMA, fp32 inputs converted at staging)
// + bias + ReLU + per-block pool partials (plain stores, no atomics).
// LDS: xs[(row*66+col)*32 + (c ^ (((col>>3)&3)<<3))] — XOR swizzle keeps
// 8-channel A-fragments contiguous (single ds_read_b128) while spreading
// staging writes across banks.
// Staging: all 20 float4 global loads issued up-front (fully unrolled,
// static indices) so the HBM-bound staging phase has 20 loads in flight per
// thread; conversion/ds_write then drains them as vmcnt counts down.
// ---------------------------------------------------------------------------
__global__ __launch_bounds__(256, 2)
void conv_pool_kernel(const float* __restrict__ x,
                      const float* __restrict__ conv_b,
                      const ushort_t* __restrict__ w_t,
                      float* __restrict__ partials) {
    __shared__ ushort_t xs[10 * 66 * 32];   // 42,240 B
    __shared__ float psum[4][64];

    const int tid = threadIdx.x;
    const int n   = blockIdx.x >> 3;        // image 0..511
    const int h0  = (blockIdx.x & 7) << 3;  // first output row
    const long xbase = (long)n * (CIN * 64 * 64);

    // ---- stage rows h0-1..h0+8 (circular): fp32 NCHW -> swizzled bf16 [h][w][c]
    {
        const int wq  = tid & 15;
        const int cg  = (tid >> 4) & 7;
        const int lr0 = tid >> 7;

        union F4 { float4 v; float f[4]; };
        F4 L[5][4];
        #pragma unroll
        for (int k = 0; k < 5; ++k) {
            const int gh = (h0 + lr0 + 2 * k + 63) & 63;
            #pragma unroll
            for (int cc = 0; cc < 4; ++cc)
                L[k][cc].v = *(const float4*)(x + xbase +
                            ((cg * 4 + cc) * 4096 + gh * 64 + wq * 4));
        }

        #pragma unroll
        for (int k = 0; k < 5; ++k) {
            const int lr = lr0 + 2 * k;
            #pragma unroll
            for (int j = 0; j < 4; ++j) {
                int col  = wq * 4 + 1 + j;                    // LDS col = w + 1
                int cpos = (cg * 4) ^ (((col >> 3) & 3) << 3);
                union { uint2 v; ushort_t s[4]; } t;
                t.s[0] = f2bf(L[k][0].f[j]); t.s[1] = f2bf(L[k][1].f[j]);
                t.s[2] = f2bf(L[k][2].f[j]); t.s[3] = f2bf(L[k][3].f[j]);
                *(uint2*)&xs[(lr * 66 + col) * 32 + cpos] = t.v;
                if (wq == 0 && j == 0)      // global w=0 -> halo col 65 (swz=0)
                    *(uint2*)&xs[(lr * 66 + 65) * 32 + cg * 4] = t.v;
                if (wq == 15 && j == 3)     // global w=63 -> halo col 0 (swz=0)
                    *(uint2*)&xs[(lr * 66 + 0) * 32 + cg * 4] = t.v;
            }
        }
    }
    __syncthreads();

    // ---- MFMA K-loop: 9 taps x K=32 channels ----
    const int lane = tid & 63;
    const int wv   = tid >> 6;
    const int m16  = lane & 15;
    const int q    = lane >> 4;

    int aaddr[8][3];
    #pragma unroll
    for (int mt = 0; mt < 8; ++mt) {
        int lpr = wv * 2 + (mt >> 2);        // local output row 0..7
        int lc  = (mt & 3) * 16 + m16;       // output col 0..63
        #pragma unroll
        for (int s = 0; s < 3; ++s) {
            int col = lc + s;
            int cr  = (q ^ ((col >> 3) & 3)) << 3;
            aaddr[mt][s] = (lpr * 66 + col) * 32 + cr;
        }
    }

    float4v accv[8][4];
    #pragma unroll
    for (int mt = 0; mt < 8; ++mt)
        #pragma unroll
        for (int nt = 0; nt < 4; ++nt)
            accv[mt][nt] = (float4v){0.f, 0.f, 0.f, 0.f};

    const ushort_t* wt_lane = w_t + (m16 * 32 + (q << 3));

    #pragma unroll
    for (int r = 0; r < 3; ++r) {
        #pragma unroll
        for (int s = 0; s < 3; ++s) {
            const int rs = r * 3 + s;
            short8v bfr[4];
            #pragma unroll
            for (int nt = 0; nt < 4; ++nt)
                bfr[nt] = *(const short8v*)(wt_lane + (rs * 64 + nt * 16) * 32);
            #pragma unroll
            for (int mt = 0; mt < 8; ++mt) {
                short8v afr = *(const short8v*)&xs[aaddr[mt][s] + r * (66 * 32)];
                #pragma unroll
                for (int nt = 0; nt < 4; ++nt)
                    accv[mt][nt] = __builtin_amdgcn_mfma_f32_16x16x32_bf16(
                        afr, bfr[nt], accv[mt][nt], 0, 0, 0);
            }
        }
    }

    // ---- epilogue: bias + ReLU + pool partial ----
    // D: out-ch n(col) = nt*16 + (lane&15); pixel m(row) = q*4 + reg.
    float sums[4] = {0.f, 0.f, 0.f, 0.f};
    #pragma unroll
    for (int nt = 0; nt < 4; ++nt) {
        float bias = conv_b[nt * 16 + m16];
        #pragma unroll
        for (int mt = 0; mt < 8; ++mt)
            #pragma unroll
            for (int rg = 0; rg < 4; ++rg)
                sums[nt] += fmaxf(accv[mt][nt][rg] + bias, 0.f);
    }
    #pragma unroll
    for (int nt = 0; nt < 4; ++nt) {
        float sv = sums[nt];
        sv += __shfl_xor(sv, 16);
        sv += __shfl_xor(sv, 32);
        if (lane < 16) psum[wv][nt * 16 + lane] = sv;
    }
    __syncthreads();
    if (tid < 64)
        partials[(long)blockIdx.x * 64 + tid] =
            psum[0][tid] + psum[1][tid] + psum[2][tid] + psum[3][tid];
}

// ---------------------------------------------------------------------------
// Kernel 3: graph MLP, one block per (batch b, recv node j) -> 512 blocks
// (2 blocks/CU). Each phase is exactly 1 element/thread.
// nodes[p][h] = sum_hb partials[((p*128+b)*8+hb)*64+h] / 4096.
// ---------------------------------------------------------------------------
__global__ __launch_bounds__(256)
void mlp_kernel(const float* __restrict__ partials,
                const float* __restrict__ e_w1, const float* __restrict__ e_b1,
                const float* __restrict__ e_w2, const float* __restrict__ e_b2,
                const float* __restrict__ o_w1, const float* __restrict__ o_b1,
                const float* __restrict__ o_w2, const float* __restrict__ o_b2,
                float* __restrict__ out) {
    __shared__ float nodes_s[256], h1s[256], e2s[256], msgs[64];

    const int tid = threadIdx.x;
    const int b   = blockIdx.x >> 2;   // batch 0..127
    const int j   = blockIdx.x & 3;    // recv node 0..3
    const int i   = tid >> 6;          // send node 0..3 (one per wave)
    const int h   = tid & 63;          // hidden lane

    // nodes for all 4 senders (recv j is one of them)
    {
        const float* pp = partials + (long)((i * 128 + b) * 8) * 64 + h;
        float s = 0.f;
        #pragma unroll
        for (int hb = 0; hb < 8; ++hb) s += pp[hb * 64];
        nodes_s[tid] = s * (1.f / 4096.f);
    }
    __syncthreads();

    // h1 for the 4 edges (i, j): [node_i(send) | node_j(recv)] @ e_w1
    {
        float sum = e_b1[h];
        const float* ni = &nodes_s[i * 64];
        const float* nj = &nodes_s[j * 64];
        #pragma unroll
        for (int k = 0; k < 64; ++k)
            sum += ni[k] * e_w1[k * 64 + h] + nj[k] * e_w1[(64 + k) * 64 + h];
        h1s[tid] = fmaxf(sum, 0.f);
    }
    __syncthreads();

    // e2 = relu(h1 @ e_w2 + e_b2)
    {
        float sum = e_b2[h];
        const float* he = &h1s[i * 64];
        #pragma unroll
        for (int k = 0; k < 64; ++k)
            sum += he[k] * e_w2[k * 64 + h];
        e2s[tid] = fmaxf(sum, 0.f);
    }
    __syncthreads();

    // msg[j] = mean over send axis i
    if (tid < 64)
        msgs[tid] = 0.25f * (e2s[tid] + e2s[64 + tid] +
                             e2s[128 + tid] + e2s[192 + tid]);
    __syncthreads();

    // o1 = relu(msg @ o_w1 + o_b1); out[b][j] = o1 . o_w2 + o_b2 (wave 0)
    if (tid < 64) {
        float sum = o_b1[tid];
        #pragma unroll
        for (int k = 0; k < 64; ++k)
            sum += msgs[k] * o_w1[k * 64 + tid];
        float v = fmaxf(sum, 0.f) * o_w2[tid];
        v += __shfl_xor(v, 1);
        v += __shfl_xor(v, 2);
        v += __shfl_xor(v, 4);
        v += __shfl_xor(v, 8);
        v += __shfl_xor(v, 16);
        v += __shfl_xor(v, 32);
        if (tid == 0) out[b * 4 + j] = v + o_b2[0];
    }
}

// ---------------------------------------------------------------------------
extern "C" void kernel_launch(void* const* d_in, const int* in_sizes, int n_in,
                              void* d_out, int out_size, void* d_ws, size_t ws_size,
                              hipStream_t stream) {
    const float* x      = (const float*)d_in[0];
    const float* conv_w = (const float*)d_in[1];
    const float* conv_b = (const float*)d_in[2];
    const float* e_w1   = (const float*)d_in[3];
    const float* e_b1   = (const float*)d_in[4];
    const float* e_w2   = (const float*)d_in[5];
    const float* e_b2   = (const float*)d_in[6];
    const float* o_w1   = (const float*)d_in[7];
    const float* o_b1   = (const float*)d_in[8];
    const float* o_w2   = (const float*)d_in[9];
    const float* o_b2   = (const float*)d_in[10];

    // ws: [0, 1MB) fp32 pool partials [4096 blocks][64ch]; then w_t bf16 (36KB)
    float*    partials = (float*)d_ws;
    ushort_t* w_t = (ushort_t*)((char*)d_ws + (size_t)NIMG * 8 * 64 * sizeof(float));

    prep_kernel<<<72, 256, 0, stream>>>(conv_w, w_t);
    conv_pool_kernel<<<NIMG * 8, 256, 0, stream>>>(x, conv_b, w_t, partials);
    mlp_kernel<<<NB * NP, 256, 0, stream>>>(partials, e_w1, e_b1, e_w2, e_b2,
                                            o_w1, o_b1, o_w2, o_b2,
                                            (float*)d_out);
}

// Round 4
// 415.841 us; speedup vs baseline: 1.7442x; 1.0122x over previous
//
#include <hip/hip_runtime.h>
#include <hip/hip_bf16.h>

typedef unsigned short ushort_t;
typedef __attribute__((ext_vector_type(8))) short short8v;
typedef __attribute__((ext_vector_type(4))) float float4v;

#define NP   4
#define NB   128
#define NIMG 512   // NP*NB
#define CIN  32
#define KOUT 64

// fp32 -> bf16 round-to-nearest-even
__device__ __forceinline__ ushort_t f2bf(float f) {
    unsigned u = __float_as_uint(f);
    unsigned r = u + 0x7fffu + ((u >> 16) & 1u);
    return (ushort_t)(r >> 16);
}

// ---------------------------------------------------------------------------
// Kernel 1: w_t[rs][outk][c] (bf16) from fp32 conv_w[outk][c][r][s], rs=r*3+s.
// B^T (n-major, k-inner) layout for the MFMA B-fragment.
// ---------------------------------------------------------------------------
__global__ void prep_kernel(const float* __restrict__ conv_w,
                            ushort_t* __restrict__ w_t) {
    int i = blockIdx.x * 256 + threadIdx.x;
    if (i < 9 * KOUT * CIN) {
        int rs  = i >> 11;
        int rem = i & 2047;
        int ko  = rem >> 5;
        int c   = rem & 31;
        w_t[i] = f2bf(conv_w[ko * 288 + c * 9 + rs]);
    }
}

// ---------------------------------------------------------------------------
// Kernel 2 (R1 register structure — frozen. R2 post-mortem: any growth of the
// accumulator live range at __launch_bounds__(256,2) spills the acc tile to
// scratch: WRITE_SIZE 1.07 GB, 448 us/dispatch. 128 AGPR acc + 128 VGPR fits
// the 256-reg unified budget exactly. DO NOT restructure the MFMA loop.)
//
// R4 change: XCD-aware block swizzle (T1). Hardware round-robins consecutive
// blockIdx across the 8 XCDs, so the 8 strips of one image landed on 8
// DIFFERENT XCDs and the 2-row halo shared by adjacent strips (67 MB of the
// 335.5 MB x-traffic) could never hit the per-XCD L2. Remap
// rb = (bid&7)*512 + (bid>>3) (bijective, 4096%8==0): each XCD owns 64 whole
// images; adjacent strips run near-concurrently on the same XCD and halo rows
// hit L2. partials indexed by rb so the mlp kernel is unchanged.
//
// Fused circular 3x3 conv (bf16 MFMA, fp32 inputs converted at staging)
// + bias + ReLU + per-block pool partials (plain stores, no atomics).
// LDS: xs[(row*66+col)*32 + (c ^ (((col>>3)&3)<<3))] — XOR swizzle keeps
// 8-channel A-fragments contiguous (single ds_read_b128) while spreading
// staging writes across banks.
// Staging: all 20 float4 global loads issued up-front (fully unrolled,
// static indices) so the HBM-bound staging phase has 20 loads in flight per
// thread; conversion/ds_write then drains them as vmcnt counts down.
// ---------------------------------------------------------------------------
__global__ __launch_bounds__(256, 2)
void conv_pool_kernel(const float* __restrict__ x,
                      const float* __restrict__ conv_b,
                      const ushort_t* __restrict__ w_t,
                      float* __restrict__ partials) {
    __shared__ ushort_t xs[10 * 66 * 32];   // 42,240 B
    __shared__ float psum[4][64];

    const int tid = threadIdx.x;
    const int bid = (int)blockIdx.x;
    const int rb  = (bid & 7) * 512 + (bid >> 3);   // XCD-contiguous remap
    const int n   = rb >> 3;                // image 0..511
    const int h0  = (rb & 7) << 3;          // first output row
    const long xbase = (long)n * (CIN * 64 * 64);

    // ---- stage rows h0-1..h0+8 (circular): fp32 NCHW -> swizzled bf16 [h][w][c]
    {
        const int wq  = tid & 15;
        const int cg  = (tid >> 4) & 7;
        const int lr0 = tid >> 7;

        union F4 { float4 v; float f[4]; };
        F4 L[5][4];
        #pragma unroll
        for (int k = 0; k < 5; ++k) {
            const int gh = (h0 + lr0 + 2 * k + 63) & 63;
            #pragma unroll
            for (int cc = 0; cc < 4; ++cc)
                L[k][cc].v = *(const float4*)(x + xbase +
                            ((cg * 4 + cc) * 4096 + gh * 64 + wq * 4));
        }

        #pragma unroll
        for (int k = 0; k < 5; ++k) {
            const int lr = lr0 + 2 * k;
            #pragma unroll
            for (int j = 0; j < 4; ++j) {
                int col  = wq * 4 + 1 + j;                    // LDS col = w + 1
                int cpos = (cg * 4) ^ (((col >> 3) & 3) << 3);
                union { uint2 v; ushort_t s[4]; } t;
                t.s[0] = f2bf(L[k][0].f[j]); t.s[1] = f2bf(L[k][1].f[j]);
                t.s[2] = f2bf(L[k][2].f[j]); t.s[3] = f2bf(L[k][3].f[j]);
                *(uint2*)&xs[(lr * 66 + col) * 32 + cpos] = t.v;
                if (wq == 0 && j == 0)      // global w=0 -> halo col 65 (swz=0)
                    *(uint2*)&xs[(lr * 66 + 65) * 32 + cg * 4] = t.v;
                if (wq == 15 && j == 3)     // global w=63 -> halo col 0 (swz=0)
                    *(uint2*)&xs[(lr * 66 + 0) * 32 + cg * 4] = t.v;
            }
        }
    }
    __syncthreads();

    // ---- MFMA K-loop: 9 taps x K=32 channels ----
    const int lane = tid & 63;
    const int wv   = tid >> 6;
    const int m16  = lane & 15;
    const int q    = lane >> 4;

    int aaddr[8][3];
    #pragma unroll
    for (int mt = 0; mt < 8; ++mt) {
        int lpr = wv * 2 + (mt >> 2);        // local output row 0..7
        int lc  = (mt & 3) * 16 + m16;       // output col 0..63
        #pragma unroll
        for (int s = 0; s < 3; ++s) {
            int col = lc + s;
            int cr  = (q ^ ((col >> 3) & 3)) << 3;
            aaddr[mt][s] = (lpr * 66 + col) * 32 + cr;
        }
    }

    float4v accv[8][4];
    #pragma unroll
    for (int mt = 0; mt < 8; ++mt)
        #pragma unroll
        for (int nt = 0; nt < 4; ++nt)
            accv[mt][nt] = (float4v){0.f, 0.f, 0.f, 0.f};

    const ushort_t* wt_lane = w_t + (m16 * 32 + (q << 3));

    #pragma unroll
    for (int r = 0; r < 3; ++r) {
        #pragma unroll
        for (int s = 0; s < 3; ++s) {
            const int rs = r * 3 + s;
            short8v bfr[4];
            #pragma unroll
            for (int nt = 0; nt < 4; ++nt)
                bfr[nt] = *(const short8v*)(wt_lane + (rs * 64 + nt * 16) * 32);
            #pragma unroll
            for (int mt = 0; mt < 8; ++mt) {
                short8v afr = *(const short8v*)&xs[aaddr[mt][s] + r * (66 * 32)];
                #pragma unroll
                for (int nt = 0; nt < 4; ++nt)
                    accv[mt][nt] = __builtin_amdgcn_mfma_f32_16x16x32_bf16(
                        afr, bfr[nt], accv[mt][nt], 0, 0, 0);
            }
        }
    }

    // ---- epilogue: bias + ReLU + pool partial ----
    // D: out-ch n(col) = nt*16 + (lane&15); pixel m(row) = q*4 + reg.
    float sums[4] = {0.f, 0.f, 0.f, 0.f};
    #pragma unroll
    for (int nt = 0; nt < 4; ++nt) {
        float bias = conv_b[nt * 16 + m16];
        #pragma unroll
        for (int mt = 0; mt < 8; ++mt)
            #pragma unroll
            for (int rg = 0; rg < 4; ++rg)
                sums[nt] += fmaxf(accv[mt][nt][rg] + bias, 0.f);
    }
    #pragma unroll
    for (int nt = 0; nt < 4; ++nt) {
        float sv = sums[nt];
        sv += __shfl_xor(sv, 16);
        sv += __shfl_xor(sv, 32);
        if (lane < 16) psum[wv][nt * 16 + lane] = sv;
    }
    __syncthreads();
    if (tid < 64)
        partials[(long)rb * 64 + tid] =
            psum[0][tid] + psum[1][tid] + psum[2][tid] + psum[3][tid];
}

// ---------------------------------------------------------------------------
// Kernel 3: graph MLP, one block per (batch b, recv node j) -> 512 blocks
// (2 blocks/CU). Each phase is exactly 1 element/thread.
// nodes[p][h] = sum_hb partials[((p*128+b)*8+hb)*64+h] / 4096.
// ---------------------------------------------------------------------------
__global__ __launch_bounds__(256)
void mlp_kernel(const float* __restrict__ partials,
                const float* __restrict__ e_w1, const float* __restrict__ e_b1,
                const float* __restrict__ e_w2, const float* __restrict__ e_b2,
                const float* __restrict__ o_w1, const float* __restrict__ o_b1,
                const float* __restrict__ o_w2, const float* __restrict__ o_b2,
                float* __restrict__ out) {
    __shared__ float nodes_s[256], h1s[256], e2s[256], msgs[64];

    const int tid = threadIdx.x;
    const int b   = blockIdx.x >> 2;   // batch 0..127
    const int j   = blockIdx.x & 3;    // recv node 0..3
    const int i   = tid >> 6;          // send node 0..3 (one per wave)
    const int h   = tid & 63;          // hidden lane

    // nodes for all 4 senders (recv j is one of them)
    {
        const float* pp = partials + (long)((i * 128 + b) * 8) * 64 + h;
        float s = 0.f;
        #pragma unroll
        for (int hb = 0; hb < 8; ++hb) s += pp[hb * 64];
        nodes_s[tid] = s * (1.f / 4096.f);
    }
    __syncthreads();

    // h1 for the 4 edges (i, j): [node_i(send) | node_j(recv)] @ e_w1
    {
        float sum = e_b1[h];
        const float* ni = &nodes_s[i * 64];
        const float* nj = &nodes_s[j * 64];
        #pragma unroll
        for (int k = 0; k < 64; ++k)
            sum += ni[k] * e_w1[k * 64 + h] + nj[k] * e_w1[(64 + k) * 64 + h];
        h1s[tid] = fmaxf(sum, 0.f);
    }
    __syncthreads();

    // e2 = relu(h1 @ e_w2 + e_b2)
    {
        float sum = e_b2[h];
        const float* he = &h1s[i * 64];
        #pragma unroll
        for (int k = 0; k < 64; ++k)
            sum += he[k] * e_w2[k * 64 + h];
        e2s[tid] = fmaxf(sum, 0.f);
    }
    __syncthreads();

    // msg[j] = mean over send axis i
    if (tid < 64)
        msgs[tid] = 0.25f * (e2s[tid] + e2s[64 + tid] +
                             e2s[128 + tid] + e2s[192 + tid]);
    __syncthreads();

    // o1 = relu(msg @ o_w1 + o_b1); out[b][j] = o1 . o_w2 + o_b2 (wave 0)
    if (tid < 64) {
        float sum = o_b1[tid];
        #pragma unroll
        for (int k = 0; k < 64; ++k)
            sum += msgs[k] * o_w1[k * 64 + tid];
        float v = fmaxf(sum, 0.f) * o_w2[tid];
        v += __shfl_xor(v, 1);
        v += __shfl_xor(v, 2);
        v += __shfl_xor(v, 4);
        v += __shfl_xor(v, 8);
        v += __shfl_xor(v, 16);
        v += __shfl_xor(v, 32);
        if (tid == 0) out[b * 4 + j] = v + o_b2[0];
    }
}

// ---------------------------------------------------------------------------
extern "C" void kernel_launch(void* const* d_in, const int* in_sizes, int n_in,
                              void* d_out, int out_size, void* d_ws, size_t ws_size,
                              hipStream_t stream) {
    const float* x      = (const float*)d_in[0];
    const float* conv_w = (const float*)d_in[1];
    const float* conv_b = (const float*)d_in[2];
    const float* e_w1   = (const float*)d_in[3];
    const float* e_b1   = (const float*)d_in[4];
    const float* e_w2   = (const float*)d_in[5];
    const float* e_b2   = (const float*)d_in[6];
    const float* o_w1   = (const float*)d_in[7];
    const float* o_b1   = (const float*)d_in[8];
    const float* o_w2   = (const float*)d_in[9];
    const float* o_b2   = (const float*)d_in[10];

    // ws: [0, 1MB) fp32 pool partials [4096 blocks][64ch]; then w_t bf16 (36KB)
    float*    partials = (float*)d_ws;
    ushort_t* w_t = (ushort_t*)((char*)d_ws + (size_t)NIMG * 8 * 64 * sizeof(float));

    prep_kernel<<<72, 256, 0, stream>>>(conv_w, w_t);
    conv_pool_kernel<<<NIMG * 8, 256, 0, stream>>>(x, conv_b, w_t, partials);
    mlp_kernel<<<NB * NP, 256, 0, stream>>>(partials, e_w1, e_b1, e_w2, e_b2,
                                            o_w1, o_b1, o_w2, o_b2,
                                            (float*)d_out);
}